// Round 4
// baseline (16098.727 us; speedup 1.0000x reference)
//
#include <hip/hip_runtime.h>

#define NTIME   101
#define BATCH   4096
#define DIM     64
#define WIDTH   256
#define TB      16
#define NTHREADS 1024
#define AST     264   // A-split LDS row stride in halves: 528 B, 16B-aligned

// Tsit5 coefficients
#define A21 0.161f
#define A31 (-0.008480655492356989f)
#define A32 0.335480655492357f
#define A41 2.8971530571054935f
#define A42 (-6.359448489975075f)
#define A43 4.3622954328695815f
#define A51 5.325864828439257f
#define A52 (-11.748883564062828f)
#define A53 7.4955393428898365f
#define A54 (-0.09249506636175525f)
#define A61 5.86145544294642f
#define A62 (-12.92096931784711f)
#define A63 8.159367898576159f
#define A64 (-0.071584973281401f)
#define A65 (-0.028269050394068383f)
#define B1 0.09646076681806523f
#define B2 0.01f
#define B3 0.4798896504144996f
#define B4 1.379008574103742f
#define B5 (-3.290069515436081f)
#define B6 2.324710524099774f

typedef float  floatx4 __attribute__((ext_vector_type(4)));
typedef _Float16 halfx8 __attribute__((ext_vector_type(8)));

// packed-weight segment offsets in d_ws (in _Float16 elements)
#define L0S1 0
#define L0S2 16384
#define L1S1 32768
#define L1S2 98304
#define L2S1 163840
#define L2S2 229376
#define L3S1 294912
#define L3S2 311296

__device__ __forceinline__ float fast_tanh(float x) {
    float e = __expf(2.0f * x);
    return 1.0f - 2.0f / (e + 1.0f);
}

// lgkm-only barrier: LDS producer->consumer visibility without draining vmcnt.
// All cross-wave communication is through LDS, so global loads (B-fragment
// prefetches) legally stay in flight across the barrier (T4).
__device__ __forceinline__ void bar_lds() {
    asm volatile("s_waitcnt lgkmcnt(0)\n\ts_barrier" ::: "memory");
}

// Split fp32 weights into scaled fp16 pairs, pack into MFMA B-fragment layout.
// Fragment block fb = nt*(K/32)+kc: 64 lanes x 8 halves; lane = q*16 + (n&15)
// supplies B[k = kc*32 + q*8 + j][n].
__global__ void pack_weights(const float* __restrict__ W0, const float* __restrict__ W1,
                             const float* __restrict__ W2, const float* __restrict__ W3,
                             _Float16* __restrict__ ws)
{
    int idx = blockIdx.x * 256 + threadIdx.x;
    const float* W; int K, N, e; size_t d1, d2;
    if (idx < 16384)       { W = W0; K = 64;  N = 256; e = idx;          d1 = L0S1; d2 = L0S2; }
    else if (idx < 81920)  { W = W1; K = 256; N = 256; e = idx - 16384;  d1 = L1S1; d2 = L1S2; }
    else if (idx < 147456) { W = W2; K = 256; N = 256; e = idx - 81920;  d1 = L2S1; d2 = L2S2; }
    else if (idx < 163840) { W = W3; K = 256; N = 64;  e = idx - 147456; d1 = L3S1; d2 = L3S2; }
    else return;
    int k = e / N, n = e % N;
    float w = W[e];
    _Float16 h1 = (_Float16)w;
    _Float16 h2 = (_Float16)((w - (float)h1) * 4096.0f);
    int kc = k >> 5, q = (k >> 3) & 3, j = k & 7, nt = n >> 4, nc = n & 15;
    size_t off = ((size_t)((nt * (K / 32) + kc) * 64 + q * 16 + nc)) * 8 + j;
    ws[d1 + off] = h1;
    ws[d2 + off] = h2;
}

// Preload chunks fb, fb+1 (cross-phase, held in regs across the barrier).
__device__ __forceinline__ void preload_b2(const _Float16* __restrict__ B1g,
                                           const _Float16* __restrict__ B2g,
                                           int fb, int lane,
                                           halfx8& o1a, halfx8& o1b,
                                           halfx8& o2a, halfx8& o2b) {
    const size_t f0 = ((size_t)fb * 64 + lane) * 8;
    const size_t f1 = ((size_t)(fb + 1) * 64 + lane) * 8;
    o1a = *(const halfx8*)(B1g + f0);
    o1b = *(const halfx8*)(B2g + f0);
    o2a = *(const halfx8*)(B1g + f1);
    o2b = *(const halfx8*)(B2g + f1);
}

// K-loop, depth-2 B prefetch via 3-slot rotation (fully unrolled -> static
// indices, rule #20). Chunks 0,1 preloaded by the PREVIOUS phase (latency
// hidden behind prior epilogue + barrier); chunk 2 issued at run start;
// chunk i+3 refilled after iter i consumes its slot.
template<int KCNT>
__device__ __forceinline__ void mfma_run_pre(const _Float16* __restrict__ pA1,
                                             const _Float16* __restrict__ pA2,
                                             const _Float16* __restrict__ B1g,
                                             const _Float16* __restrict__ B2g,
                                             int fbBase, int lane,
                                             halfx8 pb0a, halfx8 pb0b,
                                             halfx8 pb1a, halfx8 pb1b,
                                             floatx4& acc1o, floatx4& acc2o)
{
    const int m = lane & 15, q = lane >> 4;
    floatx4 acc1 = (floatx4)0.0f, acc2 = (floatx4)0.0f;
    halfx8 va1[2], va2[2], vb1[3], vb2[3];
    vb1[0] = pb0a; vb2[0] = pb0b;
    vb1[1] = pb1a; vb2[1] = pb1b;
    if (KCNT > 2) {
        const size_t f = ((size_t)(fbBase + 2) * 64 + lane) * 8;
        vb1[2] = *(const halfx8*)(B1g + f);
        vb2[2] = *(const halfx8*)(B2g + f);
    }
    const int aOff0 = m * AST + q * 8;
    va1[0] = *(const halfx8*)(pA1 + aOff0);
    va2[0] = *(const halfx8*)(pA2 + aOff0);

    #pragma unroll
    for (int i = 0; i < KCNT; ++i) {
        const int s = i % 3, an = i & 1;
        if (i + 1 < KCNT) {
            const int aOff = m * AST + (i + 1) * 32 + q * 8;
            va1[an ^ 1] = *(const halfx8*)(pA1 + aOff);
            va2[an ^ 1] = *(const halfx8*)(pA2 + aOff);
        }
        acc1 = __builtin_amdgcn_mfma_f32_16x16x32_f16(va1[an], vb1[s], acc1, 0, 0, 0);
        acc2 = __builtin_amdgcn_mfma_f32_16x16x32_f16(va1[an], vb2[s], acc2, 0, 0, 0);
        acc2 = __builtin_amdgcn_mfma_f32_16x16x32_f16(va2[an], vb1[s], acc2, 0, 0, 0);
        if (i + 3 < KCNT) {   // refill the slot just consumed with chunk i+3
            const size_t f = ((size_t)(fbBase + i + 3) * 64 + lane) * 8;
            vb1[s] = *(const halfx8*)(B1g + f);
            vb2[s] = *(const halfx8*)(B2g + f);
        }
    }
    acc1o = acc1; acc2o = acc2;
}

// L0: B fragments (2 chunks x 2 splits = 16 VGPR) are register-resident for the
// whole kernel -> zero load latency at phase start.
__device__ __forceinline__ void mfma_run_regB(const _Float16* __restrict__ pA1,
                                              const _Float16* __restrict__ pA2,
                                              int lane,
                                              const halfx8 (&b1)[2], const halfx8 (&b2)[2],
                                              floatx4& acc1o, floatx4& acc2o)
{
    const int m = lane & 15, q = lane >> 4;
    floatx4 acc1 = (floatx4)0.0f, acc2 = (floatx4)0.0f;
    const int aOff = m * AST + q * 8;
    halfx8 va1_0 = *(const halfx8*)(pA1 + aOff);
    halfx8 va2_0 = *(const halfx8*)(pA2 + aOff);
    halfx8 va1_1 = *(const halfx8*)(pA1 + aOff + 32);
    halfx8 va2_1 = *(const halfx8*)(pA2 + aOff + 32);
    acc1 = __builtin_amdgcn_mfma_f32_16x16x32_f16(va1_0, b1[0], acc1, 0, 0, 0);
    acc2 = __builtin_amdgcn_mfma_f32_16x16x32_f16(va1_0, b2[0], acc2, 0, 0, 0);
    acc2 = __builtin_amdgcn_mfma_f32_16x16x32_f16(va2_0, b1[0], acc2, 0, 0, 0);
    acc1 = __builtin_amdgcn_mfma_f32_16x16x32_f16(va1_1, b1[1], acc1, 0, 0, 0);
    acc2 = __builtin_amdgcn_mfma_f32_16x16x32_f16(va1_1, b2[1], acc2, 0, 0, 0);
    acc2 = __builtin_amdgcn_mfma_f32_16x16x32_f16(va2_1, b1[1], acc2, 0, 0, 0);
    acc1o = acc1; acc2o = acc2;
}

// Hidden-layer epilogue: combine splits, bias (register), tanh, write fp16 split planes.
__device__ __forceinline__ void hidden_epi_r(floatx4 a1, floatx4 a2, float bb,
                                             _Float16* __restrict__ o1,
                                             _Float16* __restrict__ o2,
                                             int w, int lane)
{
    const int m = lane & 15, q = lane >> 4;
    const int col = (w << 4) + m;
    #pragma unroll
    for (int v = 0; v < 4; ++v) {
        float val = fast_tanh(a1[v] + a2[v] * (1.0f / 4096.0f) + bb);
        _Float16 h1 = (_Float16)val;
        _Float16 h2 = (_Float16)((val - (float)h1) * 4096.0f);
        const int idx = (q * 4 + v) * AST + col;   // m89-verified C/D mapping
        o1[idx] = h1;
        o2[idx] = h2;
    }
}

// VGPR-budget note (R1-R3 post-mortem): the backend derives its register budget
// from the LDS-implied occupancy ceiling. At static LDS <= 81920 B two 16-wave
// WGs fit per CU -> 8 waves/EU target -> 64-VGPR cap -> the ~100-VGPR working
// set spills to scratch (R1-R3: WRITE_SIZE 5-15x, dur 2x, MfmaUtil halved).
// R3's store-only pad was DCE'd (LDS_Block_Size stayed 33792). This round the
// pad is written AND read with the value pinned by an asm keep-alive under a
// runtime-unprovable branch -> must be allocated. 33792+50176 = 83968 B > 81920
// -> 1 WG/CU -> 4 waves/EU -> 128-VGPR budget. Grid is 1 block/CU anyway.
__global__ void __launch_bounds__(NTHREADS, 4)
ode_kernel(const float* __restrict__ ts, const float* __restrict__ y0,
           const float* __restrict__ b0, const float* __restrict__ b1,
           const float* __restrict__ b2, const float* __restrict__ b3,
           const _Float16* __restrict__ ws, float* __restrict__ out)
{
    // parity-0 / parity-1 A-split buffers (the only live LDS)
    __shared__ __align__(16) _Float16 sA1[2][TB * AST];
    __shared__ __align__(16) _Float16 sA2[2][TB * AST];
    __shared__ float sPad[12544];   // occupancy limiter: 50176 B (see note above)

    const int tid  = threadIdx.x;
    const int lane = tid & 63;
    const int w    = tid >> 6;
    const int m    = lane & 15, q = lane >> 4;
    const int nt   = w & 3;
    const int col  = (w << 4) + m;    // hidden-layer column owned by this lane
    const int col3 = (nt << 4) + m;   // output (DIM) column owned by this lane
    const long base = (long)blockIdx.x * (TB * DIM);

    // Keep sPad allocated: write->read->keep-alive under a branch the compiler
    // cannot prove false (ts[0] in [0,1] at runtime). Never executes.
    if (ts[0] > 1.0e30f) {
        sPad[tid] = y0[tid];
        float z = sPad[(tid * 37) & 12287] + sPad[tid ^ 513];
        asm volatile("" :: "v"(z));
    }

    // Persistent register-resident B for L0 (fb = w*2, w*2+1)
    halfx8 L0b1[2], L0b2[2];
    #pragma unroll
    for (int i = 0; i < 2; ++i) {
        const size_t f = ((size_t)(w * 2 + i) * 64 + lane) * 8;
        L0b1[i] = *(const halfx8*)(ws + L0S1 + f);
        L0b2[i] = *(const halfx8*)(ws + L0S2 + f);
    }
    // Cross-phase prefetch registers (chunks 0,1 of the next heavy phase)
    halfx8 pbL1_0a, pbL1_0b, pbL1_1a, pbL1_1b;
    preload_b2(ws + L1S1, ws + L1S2, w * 8, lane, pbL1_0a, pbL1_0b, pbL1_1a, pbL1_1b);

    // Biases in registers (col fixed per lane for the whole kernel)
    const float bb0 = b0[col];
    const float bb1 = b1[col];
    const float bb2 = b2[col];
    const float bb3 = b3[col3];

    // Tsit5 state in registers: each lane owns 4 elements
    // (rows q*4+v, col col3) -- fixed by the MFMA C/D mapping.
    float y[4], k1[4], k2[4], k3[4], k4[4], k5[4];
    #pragma unroll
    for (int v = 0; v < 4; ++v)
        y[v] = y0[base + (q * 4 + v) * 64 + col3];

    {
        float v0 = y0[base + tid];
        __builtin_nontemporal_store(v0, &out[base + tid]);
        const int c = tid & 63, r = tid >> 6;
        _Float16 h1 = (_Float16)v0;
        _Float16 h2 = (_Float16)((v0 - (float)h1) * 4096.0f);
        sA1[0][r * AST + c] = h1;
        sA2[0][r * AST + c] = h2;
    }
    __syncthreads();

    for (int t = 0; t < NTIME - 1; ++t) {
        const float h = ts[t + 1] - ts[t];

        #pragma unroll 1
        for (int s = 0; s < 6; ++s) {
            floatx4 a1, a2;
            // L0: parity 0 -> parity 1 (register-resident B, zero phase-start load)
            mfma_run_regB(sA1[0], sA2[0], lane, L0b1, L0b2, a1, a2);
            hidden_epi_r(a1, a2, bb0, sA1[1], sA2[1], w, lane);
            bar_lds();
            // L1: parity 1 -> parity 0 (chunks 0,1 prefetched last phase)
            mfma_run_pre<8>(sA1[1], sA2[1], ws + L1S1, ws + L1S2, w * 8, lane,
                            pbL1_0a, pbL1_0b, pbL1_1a, pbL1_1b, a1, a2);
            halfx8 pbL2_0a, pbL2_0b, pbL2_1a, pbL2_1b;
            preload_b2(ws + L2S1, ws + L2S2, w * 8, lane,
                       pbL2_0a, pbL2_0b, pbL2_1a, pbL2_1b);
            hidden_epi_r(a1, a2, bb1, sA1[0], sA2[0], w, lane);
            bar_lds();
            // L2: parity 0 -> parity 1
            mfma_run_pre<8>(sA1[0], sA2[0], ws + L2S1, ws + L2S2, w * 8, lane,
                            pbL2_0a, pbL2_0b, pbL2_1a, pbL2_1b, a1, a2);
            halfx8 pbL3_0a, pbL3_0b, pbL3_1a, pbL3_1b;
            preload_b2(ws + L3S1, ws + L3S2, nt * 8, lane,
                       pbL3_0a, pbL3_0b, pbL3_1a, pbL3_1b);
            hidden_epi_r(a1, a2, bb2, sA1[1], sA2[1], w, lane);
            bar_lds();
            // L3: full-K (256), 4-way redundant across wave groups -> kv entirely
            // in registers; fused Tsit5 element update (no sP/sK/sY, one less barrier).
            mfma_run_pre<8>(sA1[1], sA2[1], ws + L3S1, ws + L3S2, nt * 8, lane,
                            pbL3_0a, pbL3_0b, pbL3_1a, pbL3_1b, a1, a2);
            preload_b2(ws + L1S1, ws + L1S2, w * 8, lane,        // next stage
                       pbL1_0a, pbL1_0b, pbL1_1a, pbL1_1b);
            float kv[4];
            #pragma unroll
            for (int v = 0; v < 4; ++v)
                kv[v] = a1[v] + a2[v] * (1.0f / 4096.0f) + bb3;

            float vn[4];
            if (s == 0) {
                #pragma unroll
                for (int v = 0; v < 4; ++v) {
                    k1[v] = kv[v];
                    vn[v] = fmaf(h, A21 * kv[v], y[v]);
                }
            } else if (s == 1) {
                #pragma unroll
                for (int v = 0; v < 4; ++v) {
                    k2[v] = kv[v];
                    vn[v] = fmaf(h, fmaf(A31, k1[v], A32 * kv[v]), y[v]);
                }
            } else if (s == 2) {
                #pragma unroll
                for (int v = 0; v < 4; ++v) {
                    k3[v] = kv[v];
                    vn[v] = fmaf(h, A41 * k1[v] + A42 * k2[v] + A43 * kv[v], y[v]);
                }
            } else if (s == 3) {
                #pragma unroll
                for (int v = 0; v < 4; ++v) {
                    k4[v] = kv[v];
                    vn[v] = fmaf(h, A51 * k1[v] + A52 * k2[v] + A53 * k3[v]
                                  + A54 * kv[v], y[v]);
                }
            } else if (s == 4) {
                #pragma unroll
                for (int v = 0; v < 4; ++v) {
                    k5[v] = kv[v];
                    vn[v] = fmaf(h, A61 * k1[v] + A62 * k2[v] + A63 * k3[v]
                                  + A64 * k4[v] + A65 * kv[v], y[v]);
                }
            } else {
                #pragma unroll
                for (int v = 0; v < 4; ++v) {
                    vn[v] = fmaf(h, B1 * k1[v] + B2 * k2[v] + B3 * k3[v]
                                  + B4 * k4[v] + B5 * k5[v] + B6 * kv[v], y[v]);
                    y[v] = vn[v];
                }
            }

            // kg==0 waves (w<4) hold a full copy of the 16x64 tile -> they alone
            // write the next-stage A splits (and the output at s==5).
            if (w < 4) {
                #pragma unroll
                for (int v = 0; v < 4; ++v) {
                    _Float16 h1 = (_Float16)vn[v];
                    _Float16 h2 = (_Float16)((vn[v] - (float)h1) * 4096.0f);
                    const int idx = (q * 4 + v) * AST + col3;
                    sA1[0][idx] = h1;
                    sA2[0][idx] = h2;
                    if (s == 5)
                        __builtin_nontemporal_store(vn[v],
                            &out[(long)(t + 1) * (BATCH * DIM) + base
                                 + (q * 4 + v) * 64 + col3]);
                }
            }
            bar_lds();
        }
    }
}

extern "C" void kernel_launch(void* const* d_in, const int* in_sizes, int n_in,
                              void* d_out, int out_size, void* d_ws, size_t ws_size,
                              hipStream_t stream) {
    (void)in_sizes; (void)n_in; (void)ws_size; (void)out_size;
    const float* ts = (const float*)d_in[0];
    const float* y0 = (const float*)d_in[1];
    const float* W0 = (const float*)d_in[2];
    const float* b0 = (const float*)d_in[3];
    const float* W1 = (const float*)d_in[4];
    const float* b1 = (const float*)d_in[5];
    const float* W2 = (const float*)d_in[6];
    const float* b2 = (const float*)d_in[7];
    const float* W3 = (const float*)d_in[8];
    const float* b3 = (const float*)d_in[9];
    _Float16* ws = (_Float16*)d_ws;
    float* out = (float*)d_out;

    hipLaunchKernelGGL(pack_weights, dim3(640), dim3(256), 0, stream, W0, W1, W2, W3, ws);
    hipLaunchKernelGGL(ode_kernel, dim3(BATCH / TB), dim3(NTHREADS), 0, stream,
                       ts, y0, b0, b1, b2, b3, ws, out);
}

// Round 5
// 4544.658 us; speedup vs baseline: 3.5423x; 3.5423x over previous
//
#include <hip/hip_runtime.h>

#define NTIME   101
#define BATCH   4096
#define DIM     64
#define WIDTH   256
#define TB      16
#define NTHREADS 1024
#define AST     264   // A-split LDS row stride in halves: 528 B, 16B-aligned
#define SPS     68    // sP row stride in floats: breaks 4-way bank conflict on partial writes

// Tsit5 coefficients
#define A21 0.161f
#define A31 (-0.008480655492356989f)
#define A32 0.335480655492357f
#define A41 2.8971530571054935f
#define A42 (-6.359448489975075f)
#define A43 4.3622954328695815f
#define A51 5.325864828439257f
#define A52 (-11.748883564062828f)
#define A53 7.4955393428898365f
#define A54 (-0.09249506636175525f)
#define A61 5.86145544294642f
#define A62 (-12.92096931784711f)
#define A63 8.159367898576159f
#define A64 (-0.071584973281401f)
#define A65 (-0.028269050394068383f)
#define B1 0.09646076681806523f
#define B2 0.01f
#define B3 0.4798896504144996f
#define B4 1.379008574103742f
#define B5 (-3.290069515436081f)
#define B6 2.324710524099774f

typedef float  floatx4 __attribute__((ext_vector_type(4)));
typedef _Float16 halfx8 __attribute__((ext_vector_type(8)));

// packed-weight segment offsets in d_ws (in _Float16 elements)
#define L0S1 0
#define L0S2 16384
#define L1S1 32768
#define L1S2 98304
#define L2S1 163840
#define L2S2 229376
#define L3S1 294912
#define L3S2 311296

__device__ __forceinline__ float fast_tanh(float x) {
    float e = __expf(2.0f * x);
    return 1.0f - 2.0f / (e + 1.0f);
}

// lgkm-only barrier: all cross-wave communication in this kernel is through
// LDS, so the barrier only needs lgkmcnt(0) -- global stores (out) and any
// in-flight global loads legally stay pending across it (T4). Avoids the
// vmcnt(0) drain __syncthreads() would emit.
__device__ __forceinline__ void bar_lds() {
    asm volatile("s_waitcnt lgkmcnt(0)\n\ts_barrier" ::: "memory");
}

// Split fp32 weights into scaled fp16 pairs, pack into MFMA B-fragment layout.
// Fragment block fb = nt*(K/32)+kc: 64 lanes x 8 halves; lane = q*16 + (n&15)
// supplies B[k = kc*32 + q*8 + j][n].
__global__ void pack_weights(const float* __restrict__ W0, const float* __restrict__ W1,
                             const float* __restrict__ W2, const float* __restrict__ W3,
                             _Float16* __restrict__ ws)
{
    int idx = blockIdx.x * 256 + threadIdx.x;
    const float* W; int K, N, e; size_t d1, d2;
    if (idx < 16384)       { W = W0; K = 64;  N = 256; e = idx;          d1 = L0S1; d2 = L0S2; }
    else if (idx < 81920)  { W = W1; K = 256; N = 256; e = idx - 16384;  d1 = L1S1; d2 = L1S2; }
    else if (idx < 147456) { W = W2; K = 256; N = 256; e = idx - 81920;  d1 = L2S1; d2 = L2S2; }
    else if (idx < 163840) { W = W3; K = 256; N = 64;  e = idx - 147456; d1 = L3S1; d2 = L3S2; }
    else return;
    int k = e / N, n = e % N;
    float w = W[e];
    _Float16 h1 = (_Float16)w;
    _Float16 h2 = (_Float16)((w - (float)h1) * 4096.0f);
    int kc = k >> 5, q = (k >> 3) & 3, j = k & 7, nt = n >> 4, nc = n & 15;
    size_t off = ((size_t)((nt * (K / 32) + kc) * 64 + q * 16 + nc)) * 8 + j;
    ws[d1 + off] = h1;
    ws[d2 + off] = h2;
}

// K-loop for one 16x16 output tile: KCNT chunks of K=32, fp16 2-split emulation.
// A splits come from LDS (ds_read_b128), B fragments from global (L2-resident),
// both software-pipelined one chunk ahead. (R0-verified: fits the 64-VGPR
// budget the backend insists on for this kernel -- do NOT add live state.)
template<int KCNT>
__device__ __forceinline__ void mfma_run(const _Float16* __restrict__ pA1,
                                         const _Float16* __restrict__ pA2,
                                         const _Float16* __restrict__ B1g,
                                         const _Float16* __restrict__ B2g,
                                         int fbBase, int kcStart, int lane,
                                         floatx4& acc1o, floatx4& acc2o)
{
    const int m = lane & 15, q = lane >> 4;
    floatx4 acc1 = (floatx4)0.0f, acc2 = (floatx4)0.0f;
    halfx8 va1[2], va2[2], vb1[2], vb2[2];

    const int aOff0 = m * AST + kcStart * 32 + q * 8;
    const size_t fOff0 = ((size_t)fbBase * 64 + lane) * 8;
    vb1[0] = *(const halfx8*)(B1g + fOff0);
    vb2[0] = *(const halfx8*)(B2g + fOff0);
    va1[0] = *(const halfx8*)(pA1 + aOff0);
    va2[0] = *(const halfx8*)(pA2 + aOff0);

    #pragma unroll
    for (int i = 0; i < KCNT; ++i) {
        const int cur = i & 1, nxt = cur ^ 1;
        if (i + 1 < KCNT) {
            const size_t fOff = ((size_t)(fbBase + i + 1) * 64 + lane) * 8;
            vb1[nxt] = *(const halfx8*)(B1g + fOff);
            vb2[nxt] = *(const halfx8*)(B2g + fOff);
            const int aOff = m * AST + (kcStart + i + 1) * 32 + q * 8;
            va1[nxt] = *(const halfx8*)(pA1 + aOff);
            va2[nxt] = *(const halfx8*)(pA2 + aOff);
        }
        acc1 = __builtin_amdgcn_mfma_f32_16x16x32_f16(va1[cur], vb1[cur], acc1, 0, 0, 0);
        acc2 = __builtin_amdgcn_mfma_f32_16x16x32_f16(va1[cur], vb2[cur], acc2, 0, 0, 0);
        acc2 = __builtin_amdgcn_mfma_f32_16x16x32_f16(va2[cur], vb1[cur], acc2, 0, 0, 0);
    }
    acc1o = acc1; acc2o = acc2;
}

// Hidden-layer epilogue: combine splits, bias, tanh, write fp16 split planes.
__device__ __forceinline__ void hidden_epi(floatx4 a1, floatx4 a2,
                                           const float* __restrict__ bias,
                                           _Float16* __restrict__ o1,
                                           _Float16* __restrict__ o2,
                                           int w, int lane)
{
    const int m = lane & 15, q = lane >> 4;
    const int col = (w << 4) + m;
    const float bb = bias[col];
    #pragma unroll
    for (int v = 0; v < 4; ++v) {
        float val = fast_tanh(a1[v] + a2[v] * (1.0f / 4096.0f) + bb);
        _Float16 h1 = (_Float16)val;
        _Float16 h2 = (_Float16)((val - (float)h1) * 4096.0f);
        const int idx = (q * 4 + v) * AST + col;   // m89-verified C/D mapping
        o1[idx] = h1;
        o2[idx] = h2;
    }
}

__global__ void __launch_bounds__(NTHREADS)
ode_kernel(const float* __restrict__ ts, const float* __restrict__ y0,
           const float* __restrict__ b0, const float* __restrict__ b1,
           const float* __restrict__ b2, const float* __restrict__ b3,
           const _Float16* __restrict__ ws, float* __restrict__ out)
{
    // parity-0 / parity-1 A-split buffers
    __shared__ __align__(16) _Float16 sA1[2][TB * AST];
    __shared__ __align__(16) _Float16 sA2[2][TB * AST];
    __shared__ __align__(16) float sK[5][TB * DIM];
    __shared__ __align__(16) float sY[TB * DIM];
    __shared__ __align__(16) float sP[4][TB * SPS];
    __shared__ __align__(16) float sBias[832];

    const int tid  = threadIdx.x;
    const int lane = tid & 63;
    const int w    = tid >> 6;
    const long base = (long)blockIdx.x * (TB * DIM);
    const int c = tid & 63;       // element column (feature)
    const int r = tid >> 6;       // element row (batch row within tile)

    if (tid < 832) {
        float v;
        if (tid < 256)      v = b0[tid];
        else if (tid < 512) v = b1[tid - 256];
        else if (tid < 768) v = b2[tid - 512];
        else                v = b3[tid - 768];
        sBias[tid] = v;
    }
    {
        float v = y0[base + tid];
        sY[tid] = v;
        __builtin_nontemporal_store(v, &out[base + tid]);
        _Float16 h1 = (_Float16)v;
        _Float16 h2 = (_Float16)((v - (float)h1) * 4096.0f);
        sA1[0][r * AST + c] = h1;
        sA2[0][r * AST + c] = h2;
    }
    __syncthreads();

    const int r68 = r * SPS + c;   // padded sP index for the elementwise phase

    for (int t = 0; t < NTIME - 1; ++t) {
        const float h = ts[t + 1] - ts[t];

        #pragma unroll 1
        for (int s = 0; s < 6; ++s) {
            floatx4 a1, a2;
            // L0: reads parity 0 (cols 0..63), writes parity 1
            mfma_run<2>(sA1[0], sA2[0], ws + L0S1, ws + L0S2, w * 2, 0, lane, a1, a2);
            hidden_epi(a1, a2, sBias + 0, sA1[1], sA2[1], w, lane);
            bar_lds();
            // L1: parity 1 -> parity 0
            mfma_run<8>(sA1[1], sA2[1], ws + L1S1, ws + L1S2, w * 8, 0, lane, a1, a2);
            hidden_epi(a1, a2, sBias + 256, sA1[0], sA2[0], w, lane);
            bar_lds();
            // L2: parity 0 -> parity 1
            mfma_run<8>(sA1[0], sA2[0], ws + L2S1, ws + L2S2, w * 8, 0, lane, a1, a2);
            hidden_epi(a1, a2, sBias + 512, sA1[1], sA2[1], w, lane);
            bar_lds();
            // L3: parity 1 -> partials in sP (4-way K-split across wave groups)
            {
                const int nt = w & 3, kg = w >> 2;
                mfma_run<2>(sA1[1], sA2[1], ws + L3S1, ws + L3S2,
                            nt * 8 + kg * 2, kg * 2, lane, a1, a2);
                const int m = lane & 15, q = lane >> 4;
                #pragma unroll
                for (int v = 0; v < 4; ++v)
                    sP[kg][(q * 4 + v) * SPS + nt * 16 + m]
                        = a1[v] + a2[v] * (1.0f / 4096.0f);
            }
            bar_lds();

            // element-wise: reduce partials -> k_s, form next stage input (or y update)
            float kv = sP[0][r68] + sP[1][r68] + sP[2][r68] + sP[3][r68]
                     + sBias[768 + c];
            float v;
            if (s == 0) {
                sK[0][tid] = kv;
                v = fmaf(h, A21 * kv, sY[tid]);
            } else if (s == 1) {
                sK[1][tid] = kv;
                v = fmaf(h, fmaf(A31, sK[0][tid], A32 * kv), sY[tid]);
            } else if (s == 2) {
                sK[2][tid] = kv;
                float sum = A41 * sK[0][tid] + A42 * sK[1][tid] + A43 * kv;
                v = fmaf(h, sum, sY[tid]);
            } else if (s == 3) {
                sK[3][tid] = kv;
                float sum = A51 * sK[0][tid] + A52 * sK[1][tid] + A53 * sK[2][tid] + A54 * kv;
                v = fmaf(h, sum, sY[tid]);
            } else if (s == 4) {
                sK[4][tid] = kv;
                float sum = A61 * sK[0][tid] + A62 * sK[1][tid] + A63 * sK[2][tid]
                          + A64 * sK[3][tid] + A65 * kv;
                v = fmaf(h, sum, sY[tid]);
            } else {
                float sum = B1 * sK[0][tid] + B2 * sK[1][tid] + B3 * sK[2][tid]
                          + B4 * sK[3][tid] + B5 * sK[4][tid] + B6 * kv;
                v = fmaf(h, sum, sY[tid]);
                sY[tid] = v;
                __builtin_nontemporal_store(v, &out[(long)(t + 1) * (BATCH * DIM) + base + tid]);
            }
            _Float16 h1 = (_Float16)v;
            _Float16 h2 = (_Float16)((v - (float)h1) * 4096.0f);
            sA1[0][r * AST + c] = h1;
            sA2[0][r * AST + c] = h2;
            bar_lds();
        }
    }
}

extern "C" void kernel_launch(void* const* d_in, const int* in_sizes, int n_in,
                              void* d_out, int out_size, void* d_ws, size_t ws_size,
                              hipStream_t stream) {
    (void)in_sizes; (void)n_in; (void)ws_size; (void)out_size;
    const float* ts = (const float*)d_in[0];
    const float* y0 = (const float*)d_in[1];
    const float* W0 = (const float*)d_in[2];
    const float* b0 = (const float*)d_in[3];
    const float* W1 = (const float*)d_in[4];
    const float* b1 = (const float*)d_in[5];
    const float* W2 = (const float*)d_in[6];
    const float* b2 = (const float*)d_in[7];
    const float* W3 = (const float*)d_in[8];
    const float* b3 = (const float*)d_in[9];
    _Float16* ws = (_Float16*)d_ws;
    float* out = (float*)d_out;

    hipLaunchKernelGGL(pack_weights, dim3(640), dim3(256), 0, stream, W0, W1, W2, W3, ws);
    hipLaunchKernelGGL(ode_kernel, dim3(BATCH / TB), dim3(NTHREADS), 0, stream,
                       ts, y0, b0, b1, b2, b3, ws, out);
}